// Round 1
// 541.477 us; speedup vs baseline: 1.2361x; 1.2361x over previous
//
#include <hip/hip_runtime.h>
#include <math.h>

#define TBB 32
#define CC  256
#define NN  196
#define NJ  (TBB * NN)            // 6272
#define HD  1024
#define SLAB   ((size_t)TBB * CC * NN)   // 1,605,632
#define SLAB1K ((size_t)TBB * HD * NN)   // 6,422,528

struct Ptr6  { const float* p[6]; };
struct PtrM6 { float*       p[6]; };

struct GArg {
    const float* W;  const float* In;
    const float* W2; const float* In2;
    const float* bias; const float* bias2;
    float* Z;
};
struct GArgs { GArg a[6]; };

// async global->LDS, 16B per lane, LDS dest = wave-uniform base + lane*16
__device__ __forceinline__ void async_copy16(const float* gsrc, float* ldst)
{
    typedef __attribute__((address_space(1))) void GV;
    typedef __attribute__((address_space(3))) void LV;
    __builtin_amdgcn_global_load_lds((GV*)const_cast<float*>(gsrc), (LV*)ldst,
                                     16, 0, 0);
}

// ---------------------------------------------------------------------------
// GEMM: Z[m, d, n] = sum_c W[d,c] * In[m, c, n]  (optional pass 2 with W2/In2
// accumulated into the same accumulators; optional bias/bias2).
// Columns flattened j = m*196 + n; NJ = 6272 = 98 * 64.
// 64x64 tile, 256 threads, 4x4 micro-tile, K-tile 16, DOUBLE-buffered LDS,
// B staged via global_load_lds dwordx4, one barrier per K-tile.
// mode 0: write z (+bias).  mode 1: write LIF spike (z >= 1).
// K accumulation order is bit-identical to the previous kernel.
// ---------------------------------------------------------------------------
__global__ __launch_bounds__(256) void gemm2(GArgs ga, int Cout, int Cin, int mode)
{
    __shared__ __align__(16) float As[2][16][68];   // padded: conflict-free staging
    __shared__ __align__(16) float Bs[2][16][64];   // wave-linear for async copy

    const GArg g = ga.a[blockIdx.z];
    const int t  = threadIdx.x;
    const int tx = t & 15, ty = t >> 4;
    const int d0 = blockIdx.x * 64;
    const int j0 = blockIdx.y * 64;
    const int lane = t & 63, wave = t >> 6;

    // A staging roles (reg -> transposed LDS write)
    const int wrow = t >> 2;          // 0..63  (W row within tile)
    const int wk   = (t & 3) * 4;     // 0,4,8,12 (K offset, float4)

    // B staging: lane's 4 columns are contiguous & 16B-aligned (196 % 4 == 0,
    // 196*4B = 49*16B), and never cross an m boundary.
    const int brow = wave * 4 + (lane >> 4);   // K row 0..15
    const int bj   = j0 + (lane & 15) * 4;
    const int bm   = bj / NN;
    const int bn   = bj - bm * NN;
    const size_t bbase = (size_t)bm * Cin * NN + bn;
    float* bdst0 = &Bs[0][wave * 4][0];        // wave-uniform LDS bases
    float* bdst1 = &Bs[1][wave * 4][0];

    float acc[4][4] = {{0.f}};
    float4 wreg;

    for (int pass = 0; pass < 2; ++pass) {
        const float* Wp = pass ? g.W2 : g.W;
        const float* Ip = pass ? g.In2 : g.In;
        if (Wp == nullptr) break;
        const int nkt = Cin >> 4;
        const size_t wbase = (size_t)(d0 + wrow) * Cin + wk;

        // prologue: stage K-tile 0 into buffer 0
        async_copy16(Ip + bbase + (size_t)brow * NN, bdst0);
        wreg = *(const float4*)(Wp + wbase);
        As[0][wk + 0][wrow] = wreg.x;
        As[0][wk + 1][wrow] = wreg.y;
        As[0][wk + 2][wrow] = wreg.z;
        As[0][wk + 3][wrow] = wreg.w;
        __syncthreads();

        for (int kt = 0; kt < nkt; ++kt) {
            const int  cur  = kt & 1;
            const int  nxt  = cur ^ 1;
            const bool more = (kt + 1) < nkt;
            if (more) {
                const int k0n = (kt + 1) << 4;
                async_copy16(Ip + bbase + (size_t)(k0n + brow) * NN,
                             nxt ? bdst1 : bdst0);
                wreg = *(const float4*)(Wp + wbase + k0n);
            }
            #pragma unroll
            for (int kk = 0; kk < 16; ++kk) {
                const float4 a4 = *(const float4*)(&As[cur][kk][ty * 4]);
                const float4 b4 = *(const float4*)(&Bs[cur][kk][tx * 4]);
                const float ar[4] = {a4.x, a4.y, a4.z, a4.w};
                const float br[4] = {b4.x, b4.y, b4.z, b4.w};
                #pragma unroll
                for (int i = 0; i < 4; ++i)
                    #pragma unroll
                    for (int jj = 0; jj < 4; ++jj)
                        acc[i][jj] = fmaf(ar[i], br[jj], acc[i][jj]);
            }
            if (more) {
                As[nxt][wk + 0][wrow] = wreg.x;
                As[nxt][wk + 1][wrow] = wreg.y;
                As[nxt][wk + 2][wrow] = wreg.z;
                As[nxt][wk + 3][wrow] = wreg.w;
            }
            __syncthreads();
        }
    }

    #pragma unroll
    for (int i = 0; i < 4; ++i) {
        const int d = d0 + ty * 4 + i;
        float bv = 0.f;
        if (g.bias)  bv += g.bias[d];
        if (g.bias2) bv += g.bias2[d];
        #pragma unroll
        for (int jj = 0; jj < 4; ++jj) {
            const int j = j0 + tx * 4 + jj;
            const int m = j / NN;
            const int n = j - m * NN;
            const float v = acc[i][jj] + bv;
            g.Z[(size_t)(m * Cout + d) * NN + n] =
                (mode == 1) ? ((v >= 1.f) ? 1.f : 0.f) : v;
        }
    }
}

// ---------------------------------------------------------------------------
// BN stats: per channel d, over (m, n). fp64 accumulation (unchanged numerics).
// grid (Cout, nconv)
// ---------------------------------------------------------------------------
__global__ __launch_bounds__(256) void bn_stats(
    Ptr6 Zs, Ptr6 gs, Ptr6 bs, int Cout,
    float* __restrict__ scale, float* __restrict__ shift)
{
    const int d = blockIdx.x, g = blockIdx.y, t = threadIdx.x;
    const float* Z = Zs.p[g];
    double s = 0.0, s2 = 0.0;
    for (int i = t; i < NJ; i += 256) {
        int m = i / NN, n = i - m * NN;
        double v = (double)Z[(size_t)(m * Cout + d) * NN + n];
        s += v; s2 += v * v;
    }
    __shared__ double sh[256], sh2[256];
    sh[t] = s; sh2[t] = s2;
    __syncthreads();
    for (int off = 128; off > 0; off >>= 1) {
        if (t < off) { sh[t] += sh[t + off]; sh2[t] += sh2[t + off]; }
        __syncthreads();
    }
    if (t == 0) {
        double mu  = sh[0] / (double)NJ;
        double var = sh2[0] / (double)NJ - mu * mu;
        double a   = (double)gs.p[g][d] / sqrt(var + 1e-5);
        scale[g * Cout + d] = (float)a;
        shift[g * Cout + d] = (float)((double)bs.p[g][d] - mu * a);
    }
}

// spike = (scale[d]*z + shift[d] >= 1); mode 1: out = spike + Rs (residual add)
// float4-vectorized. grid (total4/256, nconv)
__global__ __launch_bounds__(256) void bn_apply2(
    Ptr6 Zs, PtrM6 Ss, Ptr6 Rs, const float* __restrict__ scale,
    const float* __restrict__ shift, int Cout, int total4, int mode)
{
    const int gix = blockIdx.y;
    const int i4  = blockIdx.x * 256 + threadIdx.x;
    if (i4 >= total4) return;
    const size_t base = (size_t)i4 * 4;
    const int d = (int)((base / NN) % (size_t)Cout);   // 4 elems share one d
    const float sc = scale[gix * Cout + d];
    const float sh = shift[gix * Cout + d];
    const float4 z = *(const float4*)(Zs.p[gix] + base);
    float4 o;
    o.x = (fmaf(sc, z.x, sh) >= 1.f) ? 1.f : 0.f;
    o.y = (fmaf(sc, z.y, sh) >= 1.f) ? 1.f : 0.f;
    o.z = (fmaf(sc, z.z, sh) >= 1.f) ? 1.f : 0.f;
    o.w = (fmaf(sc, z.w, sh) >= 1.f) ? 1.f : 0.f;
    if (mode == 1) {
        const float4 r = *(const float4*)(Rs.p[gix] + base);
        o.x += r.x; o.y += r.y; o.z += r.z; o.w += r.w;
    }
    *(float4*)(Ss.p[gix] + base) = o;
}

// ---------------------------------------------------------------------------
// Attention for one (m, h): unchanged (exact bit-packed popcount).
// ---------------------------------------------------------------------------
__global__ __launch_bounds__(256) void attention_k(
    const float* __restrict__ Q, const float* __restrict__ K,
    const float* __restrict__ V, const float* __restrict__ P,
    float* __restrict__ O)
{
    const int m = blockIdx.x;
    const int h = blockIdx.y;
    const int t = threadIdx.x;
    __shared__ unsigned int qb[196], kb[196], vb[196];
    __shared__ float Pl[841];

    if (P) { for (int i = t; i < 841; i += 256) Pl[i] = P[i]; }
    if (t < 196) {
        unsigned int q = 0, k = 0, v = 0;
        size_t base = (size_t)m * CC * NN + (size_t)h * 16 * NN + t;
        #pragma unroll
        for (int dd = 0; dd < 16; ++dd) {
            size_t off = base + (size_t)dd * NN;
            if (Q[off] > 0.5f) q |= (1u << dd);
            if (K[off] > 0.5f) k |= (1u << dd);
            if (V[off] > 0.5f) v |= (1u << dd);
        }
        qb[t] = q; kb[t] = k; vb[t] = v;
    }
    __syncthreads();

    if (t < 196) {
        int acc[16] = {0};
        const int ni = t / 14, nj = t - ni * 14;
        const unsigned int qr = qb[t];
        if (P) {
            for (int mm = 0; mm < 196; ++mm) {
                int a = __popc(qr & kb[mm]);
                int mi = mm / 14, mj = mm - mi * 14;
                float sv = (float)a + Pl[(ni - mi + 14) * 29 + (nj - mj + 14)];
                if (sv >= 1.f) {
                    unsigned int vv = vb[mm];
                    #pragma unroll
                    for (int dd = 0; dd < 16; ++dd)
                        acc[dd] += (vv >> dd) & 1;
                }
            }
        } else {
            for (int mm = 0; mm < 196; ++mm) {
                int a = __popc(qr & kb[mm]);
                if (a) {
                    unsigned int vv = vb[mm];
                    #pragma unroll
                    for (int dd = 0; dd < 16; ++dd)
                        acc[dd] += ((vv >> dd) & 1) ? a : 0;
                }
            }
        }
        size_t base = (size_t)m * CC * NN + (size_t)h * 16 * NN + t;
        #pragma unroll
        for (int dd = 0; dd < 16; ++dd)
            O[base + (size_t)dd * NN] = (acc[dd] >= 2) ? 1.f : 0.f;  // 0.25*acc >= 0.5
    }
}

extern "C" void kernel_launch(void* const* d_in, const int* in_sizes, int n_in,
                              void* d_out, int out_size, void* d_ws, size_t ws_size,
                              hipStream_t stream)
{
    const float* x     = (const float*)d_in[0];
    const float* y     = (const float*)d_in[1];
    const float* av_w  = (const float*)d_in[2];
    const float* av_g  = (const float*)d_in[3];
    const float* av_b  = (const float*)d_in[4];
    const float* va_w  = (const float*)d_in[5];
    const float* va_g  = (const float*)d_in[6];
    const float* va_b  = (const float*)d_in[7];
    const float* P_rpb = (const float*)d_in[8];
    const float* fc1_w = (const float*)d_in[9];
    const float* fc1_b = (const float*)d_in[10];
    const float* fc2_w = (const float*)d_in[11];
    const float* fc2_b = (const float*)d_in[12];
    const float* m1_w  = (const float*)d_in[13];
    const float* m1_b  = (const float*)d_in[14];
    const float* m1_g  = (const float*)d_in[15];
    const float* m1_bb = (const float*)d_in[16];
    const float* m2_w  = (const float*)d_in[17];
    const float* m2_b  = (const float*)d_in[18];
    const float* m2_g  = (const float*)d_in[19];
    const float* m2_bb = (const float*)d_in[20];
    float* out = (float*)d_out;

    float* ws    = (float*)d_ws;
    float* A     = ws;               // 6 * SLAB
    float* Bf    = A  + 6 * SLAB;    // 2 * SLAB
    float* Cf    = Bf + 2 * SLAB;    // 2 * SLAB
    float* scale = Cf + 2 * SLAB;    // 6 * 1024
    float* shift = scale + 6 * 1024;

    const size_t CC2 = (size_t)CC * CC;
    const int apply256  = (int)(SLAB / 4 / 256);     // 1568
    const int apply1024 = (int)(SLAB1K / 4 / 256);   // 6272

    // ---- Stage A: 6 first-layer convs (batched) -> A slabs --------------
    GArgs ga{};
    {
        const float* Wl[6] = { av_w, av_w + CC2, av_w + 2*CC2, va_w, va_w + CC2, va_w + 2*CC2 };
        const float* Il[6] = { x, y, y, y, x, x };
        for (int i = 0; i < 6; ++i)
            ga.a[i] = GArg{ Wl[i], Il[i], nullptr, nullptr, nullptr, nullptr, A + i*SLAB };
    }
    gemm2<<<dim3(CC/64, NJ/64, 6), 256, 0, stream>>>(ga, CC, CC, 0);

    Ptr6 Zs{}, gs{}, bs{}, Rs{}; PtrM6 Ss{};
    {
        const float* gl[6] = { av_g, av_g + CC, av_g + 2*CC, va_g, va_g + CC, va_g + 2*CC };
        const float* bl[6] = { av_b, av_b + CC, av_b + 2*CC, va_b, va_b + CC, va_b + 2*CC };
        for (int i = 0; i < 6; ++i) {
            Zs.p[i] = A + i*SLAB; Ss.p[i] = A + i*SLAB; gs.p[i] = gl[i]; bs.p[i] = bl[i];
        }
    }
    bn_stats<<<dim3(CC, 6), 256, 0, stream>>>(Zs, gs, bs, CC, scale, shift);
    bn_apply2<<<dim3(apply256, 6), 256, 0, stream>>>(Zs, Ss, Rs, scale, shift, CC, (int)(SLAB/4), 0);

    // ---- Stage B: attention (exact, bit-packed) -------------------------
    attention_k<<<dim3(TBB, 16), 256, 0, stream>>>(A, A + SLAB, A + 2*SLAB, nullptr, Bf);
    attention_k<<<dim3(TBB, 16), 256, 0, stream>>>(A + 3*SLAB, A + 4*SLAB, A + 5*SLAB, P_rpb, Bf + SLAB);

    // ---- Stage C: W3 conv (batched x2) + BN + LIF + residual -> x1,y1 ---
    GArgs gc{};
    gc.a[0] = GArg{ av_w + 3*CC2, Bf,        nullptr, nullptr, nullptr, nullptr, Cf };
    gc.a[1] = GArg{ va_w + 3*CC2, Bf + SLAB, nullptr, nullptr, nullptr, nullptr, Cf + SLAB };
    gemm2<<<dim3(CC/64, NJ/64, 2), 256, 0, stream>>>(gc, CC, CC, 0);
    Zs.p[0] = Cf; Zs.p[1] = Cf + SLAB;
    gs.p[0] = av_g + 3*CC; gs.p[1] = va_g + 3*CC;
    bs.p[0] = av_b + 3*CC; bs.p[1] = va_b + 3*CC;
    Rs.p[0] = x; Rs.p[1] = y;
    Ss.p[0] = A; Ss.p[1] = A + SLAB;          // x1, y1
    bn_stats<<<dim3(CC, 2), 256, 0, stream>>>(Zs, gs, bs, CC, scale, shift);
    bn_apply2<<<dim3(apply256, 2), 256, 0, stream>>>(Zs, Ss, Rs, scale, shift, CC, (int)(SLAB/4), 1);

    // ---- fc1@x1 + fc2@y1 + biases, fused LIF -> cur (Bf+SLAB) ----------
    GArgs gf{};
    gf.a[0] = GArg{ fc1_w, A, fc2_w, A + SLAB, fc1_b, fc2_b, Bf + SLAB };
    gemm2<<<dim3(CC/64, NJ/64, 1), 256, 0, stream>>>(gf, CC, CC, 1);

    // ---- m1: (1024x256) @ cur + BN + LIF -> h in A ---------------------
    GArgs g1{};
    g1.a[0] = GArg{ m1_w, Bf + SLAB, nullptr, nullptr, m1_b, nullptr, A };
    gemm2<<<dim3(HD/64, NJ/64, 1), 256, 0, stream>>>(g1, HD, CC, 0);
    Zs.p[0] = A; Ss.p[0] = A; gs.p[0] = m1_g; bs.p[0] = m1_bb;
    bn_stats<<<dim3(HD, 1), 256, 0, stream>>>(Zs, gs, bs, HD, scale, shift);
    bn_apply2<<<dim3(apply1024, 1), 256, 0, stream>>>(Zs, Ss, Rs, scale, shift, HD, (int)(SLAB1K/4), 0);

    // ---- m2: (256x1024) @ h + BN + LIF + (cur +) -> out ----------------
    GArgs g2{};
    g2.a[0] = GArg{ m2_w, A, nullptr, nullptr, m2_b, nullptr, Cf };
    gemm2<<<dim3(CC/64, NJ/64, 1), 256, 0, stream>>>(g2, CC, HD, 0);
    Zs.p[0] = Cf; gs.p[0] = m2_g; bs.p[0] = m2_bb;
    Rs.p[0] = Bf + SLAB;                      // cur
    Ss.p[0] = out;                            // out = cur + o  (fused)
    bn_stats<<<dim3(CC, 1), 256, 0, stream>>>(Zs, gs, bs, CC, scale, shift);
    bn_apply2<<<dim3(apply256, 1), 256, 0, stream>>>(Zs, Ss, Rs, scale, shift, CC, (int)(SLAB/4), 1);
}